// Round 2
// baseline (372.451 us; speedup 1.0000x reference)
//
#include <hip/hip_runtime.h>
#include <hip/hip_bf16.h>
#include <stdint.h>

#define S_LEN 1024
#define BATCH 2
#define DM    768
#define NH    12
#define HD    64
#define W1    32
#define WIN   65

typedef unsigned short u16;
typedef __attribute__((ext_vector_type(4))) float f4;

__device__ inline float bf2f(u16 x) {
    union { unsigned u; float f; } z;
    z.u = ((unsigned)x) << 16;
    return z.f;
}
__device__ inline u16 f2bf(float x) {
    union { float f; unsigned u; } z;
    z.f = x;
    unsigned r = z.u + 0x7FFF + ((z.u >> 16) & 1);   // RNE
    return (u16)(r >> 16);
}
// flag==1: buffer holds float32; flag==0: buffer holds bf16
__device__ inline float loadF(const void* p, long i, int f) {
    return f ? ((const float*)p)[i] : bf2f(((const u16*)p)[i]);
}

// ---------------------------------------------------------------------------
// Kernel 0: dtype detector. bf16 view of N(0,1) bf16 data: ~0 elements with
// exponent >= 134 (|v|>=128). bf16 view of f32 data: low-half u16s have
// uniform-random exponents -> ~48% weird. Threshold 32/512.
// ---------------------------------------------------------------------------
__global__ void detect_dtype(const u16* __restrict__ x, int* __restrict__ flag) {
    __shared__ int cnt;
    if (threadIdx.x == 0) cnt = 0;
    __syncthreads();
    int w = 0;
    for (int i = threadIdx.x; i < 512; i += 256) {
        int e = (x[i] >> 7) & 0xFF;
        if (e >= 134) w++;
    }
    atomicAdd(&cnt, w);
    __syncthreads();
    if (threadIdx.x == 0) *flag = (cnt >= 32) ? 1 : 0;
}

// ---------------------------------------------------------------------------
// Kernel 1: fused QKV projection, f32 VALU GEMM. 64x64 tile, 4x4 per thread.
// C[m][n] = X[m][:] . W[:][n] + bias[n], n in [0,2304) over {Wq,Wk,Wv}.
// ---------------------------------------------------------------------------
__global__ __launch_bounds__(256) void qkv_gemm_f(
    const void* __restrict__ X,
    const void* __restrict__ Wq, const void* __restrict__ Wk, const void* __restrict__ Wv,
    const void* __restrict__ bq, const void* __restrict__ bk, const void* __restrict__ bv,
    const int* __restrict__ flag,
    float* __restrict__ Qf, float* __restrict__ Kf, float* __restrict__ Vf) {
    __shared__ float Xs[64][17];   // [m][k]
    __shared__ float Ws[16][65];   // [k][n]
    const int f = *flag;
    const int t = threadIdx.x;
    const int tx = t & 15, ty = t >> 4;
    const int n0 = blockIdx.x * 64;     // 0..2240
    const int m0 = blockIdx.y * 64;     // 0..1984
    const int region = n0 / DM;
    const int nl0 = n0 % DM;
    const void* W    = (region == 0) ? Wq : ((region == 1) ? Wk : Wv);
    const void* bias = (region == 0) ? bq : ((region == 1) ? bk : bv);

    float acc[4][4];
    #pragma unroll
    for (int r = 0; r < 4; ++r)
        #pragma unroll
        for (int c = 0; c < 4; ++c) acc[r][c] = 0.f;

    for (int kk = 0; kk < DM; kk += 16) {
        #pragma unroll
        for (int p = 0; p < 4; ++p) {
            int e = p * 256 + t;                // 0..1023
            int mm = e >> 4, k1 = e & 15;
            Xs[mm][k1] = loadF(X, (long)(m0 + mm) * DM + kk + k1, f);
            int nn = e & 63, k2 = e >> 6;
            Ws[k2][nn] = loadF(W, (long)(kk + k2) * DM + nl0 + nn, f);
        }
        __syncthreads();
        #pragma unroll
        for (int k = 0; k < 16; ++k) {
            float a[4], bb[4];
            #pragma unroll
            for (int r = 0; r < 4; ++r) a[r] = Xs[ty + 16 * r][k];   // broadcast
            #pragma unroll
            for (int c = 0; c < 4; ++c) bb[c] = Ws[k][tx + 16 * c];
            #pragma unroll
            for (int r = 0; r < 4; ++r)
                #pragma unroll
                for (int c = 0; c < 4; ++c) acc[r][c] += a[r] * bb[c];
        }
        __syncthreads();
    }

    float* Out = (region == 0) ? Qf : ((region == 1) ? Kf : Vf);
    #pragma unroll
    for (int c = 0; c < 4; ++c) {
        float bv2 = loadF(bias, nl0 + tx + 16 * c, f);
        #pragma unroll
        for (int r = 0; r < 4; ++r)
            Out[(long)(m0 + ty + 16 * r) * DM + nl0 + tx + 16 * c] = acc[r][c] + bv2;
    }
}

// ---------------------------------------------------------------------------
// Kernel 2: sliding-window attention + pooled sum (all f32).
// Block: (b, h, 64 queries). Wave: 16 queries; lane=(q=lane&15, j=lane>>4).
// K window (128 rows) in padded LDS; V/Q straight from global (L1-resident).
// ---------------------------------------------------------------------------
__global__ __launch_bounds__(256) void attn_pool_f(
    const float* __restrict__ Qf, const float* __restrict__ Kf,
    const float* __restrict__ Vf, float* __restrict__ pooled) {
    __shared__ float ks[128][68];
    const int b = blockIdx.z, h = blockIdx.y;
    const int s0 = blockIdx.x * 64;
    const int t = threadIdx.x;

    #pragma unroll
    for (int p = 0; p < 8; ++p) {
        int e = p * 256 + t;                 // 0..2047
        int row = e >> 4, c4 = e & 15;
        int srow = s0 - 32 + row;
        srow = srow < 0 ? 0 : (srow >= S_LEN ? S_LEN - 1 : srow);
        f4 v = *(const f4*)&Kf[(long)(b * S_LEN + srow) * DM + h * HD + c4 * 4];
        *(f4*)&ks[row][c4 * 4] = v;
    }

    const int w = t >> 6, lane = t & 63;
    const int qloc = lane & 15, j = lane >> 4;
    const int s = s0 + w * 16 + qloc;

    float qf[16];
    {
        const float* qp = &Qf[(long)(b * S_LEN + s) * DM + h * HD + j * 16];
        #pragma unroll
        for (int dd = 0; dd < 16; ++dd) qf[dd] = qp[dd] * 0.125f;  // 1/sqrt(64)
    }
    __syncthreads();

    float l = 0.f;
    float o[16];
    #pragma unroll
    for (int dd = 0; dd < 16; ++dd) o[dd] = 0.f;
    const int base = w * 16 + qloc;

    for (int wo = 0; wo < WIN; ++wo) {
        int lkey = base + wo;                // <= 127
        float part = 0.f;
        #pragma unroll
        for (int dd = 0; dd < 16; ++dd) part += qf[dd] * ks[lkey][j * 16 + dd];
        part += __shfl_xor(part, 16, 64);
        part += __shfl_xor(part, 32, 64);
        int kabs = s - W1 + wo;
        int kc = kabs < 0 ? 0 : (kabs >= S_LEN ? S_LEN - 1 : kabs);
        float p = (kabs >= 0 && kabs < S_LEN) ? __expf(part) : 0.f;
        l += p;
        const float* vp = &Vf[(long)(b * S_LEN + kc) * DM + h * HD + j * 16];
        #pragma unroll
        for (int dd = 0; dd < 16; ++dd) o[dd] += p * vp[dd];
    }

    const float inv = 1.0f / l;
    #pragma unroll
    for (int dd = 0; dd < 16; ++dd) o[dd] *= inv;

    #pragma unroll
    for (int m = 1; m <= 8; m <<= 1)
        #pragma unroll
        for (int dd = 0; dd < 16; ++dd) o[dd] += __shfl_xor(o[dd], m, 64);

    if (qloc == 0) {
        #pragma unroll
        for (int dd = 0; dd < 16; ++dd)
            atomicAdd(&pooled[b * DM + h * HD + j * 16 + dd], o[dd]);
    }
}

// ---------------------------------------------------------------------------
// Kernel 3: out = relu(pooled/S @ Wfc + bfc); flag-based store (bf16 or f32).
// ---------------------------------------------------------------------------
__global__ __launch_bounds__(256) void fc_relu_f(
    const float* __restrict__ pooled, const void* __restrict__ Wfc,
    const void* __restrict__ bfc, const int* __restrict__ flag,
    void* __restrict__ out) {
    __shared__ float red[2][4][64];
    const int f = *flag;
    const int t = threadIdx.x;
    const int nb = blockIdx.x;          // 0..11
    const int nn = t & 63;
    const int dg = t >> 6;              // 0..3
    const int n = nb * 64 + nn;
    float s0 = 0.f, s1 = 0.f;
    for (int d = dg * 192; d < dg * 192 + 192; ++d) {
        float wv = loadF(Wfc, (long)d * DM + n, f);
        s0 += pooled[d] * wv;
        s1 += pooled[DM + d] * wv;
    }
    red[0][dg][nn] = s0;
    red[1][dg][nn] = s1;
    __syncthreads();
    if (t < 128) {
        int bb = t >> 6;
        int n2 = t & 63;
        float sum = red[bb][0][n2] + red[bb][1][n2] + red[bb][2][n2] + red[bb][3][n2];
        sum = sum * (1.0f / (float)S_LEN) + loadF(bfc, nb * 64 + n2, f);
        sum = sum > 0.f ? sum : 0.f;
        int oi = bb * DM + nb * 64 + n2;
        if (f) ((float*)out)[oi] = sum;
        else   ((u16*)out)[oi]  = f2bf(sum);
    }
}

// ---------------------------------------------------------------------------
extern "C" void kernel_launch(void* const* d_in, const int* in_sizes, int n_in,
                              void* d_out, int out_size, void* d_ws, size_t ws_size,
                              hipStream_t stream) {
    const void* X   = d_in[0];
    const void* Wq  = d_in[1];
    const void* bq  = d_in[2];
    const void* Wk  = d_in[3];
    const void* bk  = d_in[4];
    const void* Wv  = d_in[5];
    const void* bv  = d_in[6];
    const void* Wfc = d_in[7];
    const void* bfc = d_in[8];

    char* ws = (char*)d_ws;
    const size_t SZ = (size_t)BATCH * S_LEN * DM * sizeof(float);  // 6,291,456
    float* Qf = (float*)(ws);
    float* Kf = (float*)(ws + SZ);
    float* Vf = (float*)(ws + 2 * SZ);
    float* pooled = (float*)(ws + 3 * SZ);
    int* flag = (int*)(ws + 3 * SZ + BATCH * DM * sizeof(float));

    hipMemsetAsync(pooled, 0, (size_t)BATCH * DM * sizeof(float), stream);

    detect_dtype<<<1, 256, 0, stream>>>((const u16*)X, flag);

    qkv_gemm_f<<<dim3(36, 32), 256, 0, stream>>>(
        X, Wq, Wk, Wv, bq, bk, bv, flag, Qf, Kf, Vf);

    attn_pool_f<<<dim3(16, NH, BATCH), 256, 0, stream>>>(Qf, Kf, Vf, pooled);

    fc_relu_f<<<12, 256, 0, stream>>>(pooled, Wfc, bfc, flag, d_out);
}

// Round 3
// 203.573 us; speedup vs baseline: 1.8296x; 1.8296x over previous
//
#include <hip/hip_runtime.h>
#include <hip/hip_bf16.h>
#include <stdint.h>

#define S_LEN 1024
#define BATCH 2
#define DM    768
#define NH    12
#define HD    64
#define W1    32
#define WIN   65
#define NQKV  2304
#define M_TOT 2048

typedef unsigned short u16;
typedef __attribute__((ext_vector_type(4))) float f4;
typedef __attribute__((ext_vector_type(8))) unsigned short ushort8;
typedef __attribute__((ext_vector_type(8))) __bf16 bf16x8;
typedef __attribute__((ext_vector_type(4))) float f32x4;

__device__ inline float bf2f(u16 x) {
    union { unsigned u; float f; } z;
    z.u = ((unsigned)x) << 16;
    return z.f;
}
__device__ inline u16 f2bf(float x) {
    union { float f; unsigned u; } z;
    z.f = x;
    unsigned r = z.u + 0x7FFF + ((z.u >> 16) & 1);   // RNE
    return (u16)(r >> 16);
}
// flag==1: buffer holds float32; flag==0: buffer holds bf16
__device__ inline float loadF(const void* p, long i, int f) {
    return f ? ((const float*)p)[i] : bf2f(((const u16*)p)[i]);
}

// ---------------------------------------------------------------------------
// Kernel 0: dtype detector (kept for safety; confirmed f32 in R2).
// ---------------------------------------------------------------------------
__global__ void detect_dtype(const u16* __restrict__ x, int* __restrict__ flag) {
    __shared__ int cnt;
    if (threadIdx.x == 0) cnt = 0;
    __syncthreads();
    int w = 0;
    for (int i = threadIdx.x; i < 512; i += 256) {
        int e = (x[i] >> 7) & 0xFF;
        if (e >= 134) w++;
    }
    atomicAdd(&cnt, w);
    __syncthreads();
    if (threadIdx.x == 0) *flag = (cnt >= 32) ? 1 : 0;
}

// ---------------------------------------------------------------------------
// Kernel 1: X (f32 or bf16) -> Xhi, Xlo (bf16 split). 8 elems/thread.
// ---------------------------------------------------------------------------
__global__ __launch_bounds__(256) void convert_x(
    const void* __restrict__ X, const int* __restrict__ flag,
    u16* __restrict__ hi, u16* __restrict__ lo) {
    const int f = *flag;
    const long base = (long)(blockIdx.x * 256 + threadIdx.x) * 8;
    float v[8];
    if (f) {
        f4 a = *(const f4*)&((const float*)X)[base];
        f4 b = *(const f4*)&((const float*)X)[base + 4];
        v[0]=a.x; v[1]=a.y; v[2]=a.z; v[3]=a.w;
        v[4]=b.x; v[5]=b.y; v[6]=b.z; v[7]=b.w;
    } else {
        ushort8 a = *(const ushort8*)&((const u16*)X)[base];
        #pragma unroll
        for (int j = 0; j < 8; ++j) v[j] = bf2f(a[j]);
    }
    ushort8 h, l;
    #pragma unroll
    for (int j = 0; j < 8; ++j) {
        u16 hb = f2bf(v[j]);
        h[j] = hb;
        l[j] = f2bf(v[j] - bf2f(hb));
    }
    *(ushort8*)&hi[base] = h;
    *(ushort8*)&lo[base] = l;
}

// ---------------------------------------------------------------------------
// Kernel 2: transpose+concat+split weights -> Wt_hi/Wt_lo [n][k], n in [0,2304)
// ---------------------------------------------------------------------------
__global__ __launch_bounds__(256) void transpose_w(
    const void* __restrict__ Wq, const void* __restrict__ Wk,
    const void* __restrict__ Wv, const int* __restrict__ flag,
    u16* __restrict__ Whi, u16* __restrict__ Wlo) {
    __shared__ float tile[64][68];
    const int f = *flag;
    const int n0 = blockIdx.x * 64;     // 0..2240
    const int k0 = blockIdx.y * 64;     // 0..704
    const int sel = n0 / DM;
    const int nl0 = n0 % DM;
    const void* W = (sel == 0) ? Wq : ((sel == 1) ? Wk : Wv);
    const int t = threadIdx.x;
    const int r = t >> 3;               // 0..31
    const int cg = t & 7;               // 0..7

    #pragma unroll
    for (int p = 0; p < 2; ++p) {
        int rr = r + p * 32;            // source row (k)
        long gb = (long)(k0 + rr) * DM + nl0 + cg * 8;
        if (f) {
            f4 a = *(const f4*)&((const float*)W)[gb];
            f4 b = *(const f4*)&((const float*)W)[gb + 4];
            *(f4*)&tile[rr][cg * 8] = a;
            *(f4*)&tile[rr][cg * 8 + 4] = b;
        } else {
            ushort8 a = *(const ushort8*)&((const u16*)W)[gb];
            #pragma unroll
            for (int j = 0; j < 8; ++j) tile[rr][cg * 8 + j] = bf2f(a[j]);
        }
    }
    __syncthreads();
    #pragma unroll
    for (int p = 0; p < 2; ++p) {
        int rn = r + p * 32;            // output row (n)
        ushort8 h, l;
        #pragma unroll
        for (int jj = 0; jj < 8; ++jj) {
            float v = tile[cg * 8 + jj][rn];
            u16 hb = f2bf(v);
            h[jj] = hb;
            l[jj] = f2bf(v - bf2f(hb));
        }
        long ob = (long)(n0 + rn) * DM + k0 + cg * 8;
        *(ushort8*)&Whi[ob] = h;
        *(ushort8*)&Wlo[ob] = l;
    }
}

// ---------------------------------------------------------------------------
// Kernel 3: fused QKV GEMM via split-bf16 MFMA (3 products: hh + hl + lh).
// C[m][n] = X[m][:] . Wt[n][:] + bias[n].  128x128 tile, BK=64, 4 waves,
// each wave 4x4 tiles of 16x16x32. XOR-swizzled LDS.
// ---------------------------------------------------------------------------
__global__ __launch_bounds__(256) void qkv_gemm_mfma(
    const u16* __restrict__ Xhi, const u16* __restrict__ Xlo,
    const u16* __restrict__ Whi, const u16* __restrict__ Wlo,
    const void* __restrict__ bq, const void* __restrict__ bk,
    const void* __restrict__ bv, const int* __restrict__ flag,
    float* __restrict__ Qf, float* __restrict__ Kf, float* __restrict__ Vf) {
    __shared__ u16 As[2][128 * 64];   // [hi/lo][row*8+swizzled chunk][8]
    __shared__ u16 Bs[2][128 * 64];

    const int nt = blockIdx.x;      // 0..17
    const int mt = blockIdx.y;      // 0..15
    const int m0 = mt * 128;
    const int n0 = nt * 128;
    const int t = threadIdx.x;
    const int lane = t & 63;
    const int w = t >> 6;
    const int wm = (w >> 1) * 64;
    const int wn = (w & 1) * 64;
    const int lrow = lane & 15;
    const int lq = lane >> 4;
    const int smrow = t >> 3;       // 0..31
    const int skc = t & 7;          // 0..7

    const f32x4 fzero = {0.f, 0.f, 0.f, 0.f};
    f32x4 acc[4][4];
    #pragma unroll
    for (int i = 0; i < 4; ++i)
        #pragma unroll
        for (int j = 0; j < 4; ++j) acc[i][j] = fzero;

    for (int kk = 0; kk < DM; kk += 64) {
        __syncthreads();
        #pragma unroll
        for (int p = 0; p < 4; ++p) {
            int mrow = smrow + p * 32;
            int sw = skc ^ (mrow & 7);
            long ga = (long)(m0 + mrow) * DM + kk + skc * 8;
            long gb = (long)(n0 + mrow) * DM + kk + skc * 8;
            *(ushort8*)&As[0][(mrow * 8 + sw) * 8] = *(const ushort8*)&Xhi[ga];
            *(ushort8*)&As[1][(mrow * 8 + sw) * 8] = *(const ushort8*)&Xlo[ga];
            *(ushort8*)&Bs[0][(mrow * 8 + sw) * 8] = *(const ushort8*)&Whi[gb];
            *(ushort8*)&Bs[1][(mrow * 8 + sw) * 8] = *(const ushort8*)&Wlo[gb];
        }
        __syncthreads();
        #pragma unroll
        for (int kh = 0; kh < 2; ++kh) {
            const int c = kh * 4 + lq;
            bf16x8 ah[4], al[4], bh[4], bl[4];
            #pragma unroll
            for (int i = 0; i < 4; ++i) {
                int ar = wm + i * 16 + lrow;
                int off = (ar * 8 + (c ^ (ar & 7))) * 8;
                ah[i] = *(const bf16x8*)&As[0][off];
                al[i] = *(const bf16x8*)&As[1][off];
            }
            #pragma unroll
            for (int i = 0; i < 4; ++i) {
                int br = wn + i * 16 + lrow;
                int off = (br * 8 + (c ^ (br & 7))) * 8;
                bh[i] = *(const bf16x8*)&Bs[0][off];
                bl[i] = *(const bf16x8*)&Bs[1][off];
            }
            #pragma unroll
            for (int i = 0; i < 4; ++i)
                #pragma unroll
                for (int j = 0; j < 4; ++j) {
                    acc[i][j] = __builtin_amdgcn_mfma_f32_16x16x32_bf16(
                        al[i], bh[j], acc[i][j], 0, 0, 0);
                    acc[i][j] = __builtin_amdgcn_mfma_f32_16x16x32_bf16(
                        ah[i], bl[j], acc[i][j], 0, 0, 0);
                    acc[i][j] = __builtin_amdgcn_mfma_f32_16x16x32_bf16(
                        ah[i], bh[j], acc[i][j], 0, 0, 0);
                }
        }
    }

    const int f = *flag;
    const int region = n0 / DM;
    const int nc0 = (n0 % DM) + wn;
    const void* bias = (region == 0) ? bq : ((region == 1) ? bk : bv);
    float* Out = (region == 0) ? Qf : ((region == 1) ? Kf : Vf);
    #pragma unroll
    for (int j = 0; j < 4; ++j) {
        int col = nc0 + j * 16 + lrow;
        float bval = loadF(bias, col, f);
        #pragma unroll
        for (int i = 0; i < 4; ++i) {
            int row = m0 + wm + i * 16 + lq * 4;
            #pragma unroll
            for (int r = 0; r < 4; ++r)
                Out[(long)(row + r) * DM + col] = acc[i][j][r] + bval;
        }
    }
}

// ---------------------------------------------------------------------------
// Kernel 4: sliding-window attention + pooled sum (f32). K AND V in LDS.
// Block: (b, h, 64 queries). Wave: 16 queries; lane=(q=lane&15, j=lane>>4).
// ---------------------------------------------------------------------------
__global__ __launch_bounds__(256) void attn_pool_f(
    const float* __restrict__ Qf, const float* __restrict__ Kf,
    const float* __restrict__ Vf, float* __restrict__ pooled) {
    __shared__ float ks[128][68];
    __shared__ float vs[128][68];
    const int b = blockIdx.z, h = blockIdx.y;
    const int s0 = blockIdx.x * 64;
    const int t = threadIdx.x;

    #pragma unroll
    for (int p = 0; p < 8; ++p) {
        int e = p * 256 + t;                 // 0..2047
        int row = e >> 4, c4 = e & 15;
        int srow = s0 - 32 + row;
        srow = srow < 0 ? 0 : (srow >= S_LEN ? S_LEN - 1 : srow);
        long ga = (long)(b * S_LEN + srow) * DM + h * HD + c4 * 4;
        *(f4*)&ks[row][c4 * 4] = *(const f4*)&Kf[ga];
        *(f4*)&vs[row][c4 * 4] = *(const f4*)&Vf[ga];
    }

    const int w = t >> 6, lane = t & 63;
    const int qloc = lane & 15, j = lane >> 4;
    const int s = s0 + w * 16 + qloc;

    float qf[16];
    {
        const float* qp = &Qf[(long)(b * S_LEN + s) * DM + h * HD + j * 16];
        #pragma unroll
        for (int dd = 0; dd < 16; ++dd) qf[dd] = qp[dd] * 0.125f;  // 1/sqrt(64)
    }
    __syncthreads();

    float l = 0.f;
    float o[16];
    #pragma unroll
    for (int dd = 0; dd < 16; ++dd) o[dd] = 0.f;
    const int base = w * 16 + qloc;

    for (int wo = 0; wo < WIN; ++wo) {
        int lkey = base + wo;                // <= 127
        float part = 0.f;
        #pragma unroll
        for (int dd = 0; dd < 16; ++dd) part += qf[dd] * ks[lkey][j * 16 + dd];
        part += __shfl_xor(part, 16, 64);
        part += __shfl_xor(part, 32, 64);
        int kabs = s - W1 + wo;
        float p = (kabs >= 0 && kabs < S_LEN) ? __expf(part) : 0.f;
        l += p;
        #pragma unroll
        for (int dd = 0; dd < 16; ++dd) o[dd] += p * vs[lkey][j * 16 + dd];
    }

    const float inv = 1.0f / l;
    #pragma unroll
    for (int dd = 0; dd < 16; ++dd) o[dd] *= inv;

    #pragma unroll
    for (int m = 1; m <= 8; m <<= 1)
        #pragma unroll
        for (int dd = 0; dd < 16; ++dd) o[dd] += __shfl_xor(o[dd], m, 64);

    if (qloc == 0) {
        #pragma unroll
        for (int dd = 0; dd < 16; ++dd)
            atomicAdd(&pooled[b * DM + h * HD + j * 16 + dd], o[dd]);
    }
}

// ---------------------------------------------------------------------------
// Kernel 5: out = relu(pooled/S @ Wfc + bfc); flag-based load/store.
// ---------------------------------------------------------------------------
__global__ __launch_bounds__(256) void fc_relu_f(
    const float* __restrict__ pooled, const void* __restrict__ Wfc,
    const void* __restrict__ bfc, const int* __restrict__ flag,
    void* __restrict__ out) {
    __shared__ float red[2][4][64];
    const int f = *flag;
    const int t = threadIdx.x;
    const int nb = blockIdx.x;          // 0..11
    const int nn = t & 63;
    const int dg = t >> 6;              // 0..3
    const int n = nb * 64 + nn;
    float s0 = 0.f, s1 = 0.f;
    for (int d = dg * 192; d < dg * 192 + 192; ++d) {
        float wv = loadF(Wfc, (long)d * DM + n, f);
        s0 += pooled[d] * wv;
        s1 += pooled[DM + d] * wv;
    }
    red[0][dg][nn] = s0;
    red[1][dg][nn] = s1;
    __syncthreads();
    if (t < 128) {
        int bb = t >> 6;
        int n2 = t & 63;
        float sum = red[bb][0][n2] + red[bb][1][n2] + red[bb][2][n2] + red[bb][3][n2];
        sum = sum * (1.0f / (float)S_LEN) + loadF(bfc, nb * 64 + n2, f);
        sum = sum > 0.f ? sum : 0.f;
        int oi = bb * DM + nb * 64 + n2;
        if (f) ((float*)out)[oi] = sum;
        else   ((u16*)out)[oi]  = f2bf(sum);
    }
}

// ---------------------------------------------------------------------------
extern "C" void kernel_launch(void* const* d_in, const int* in_sizes, int n_in,
                              void* d_out, int out_size, void* d_ws, size_t ws_size,
                              hipStream_t stream) {
    const void* X   = d_in[0];
    const void* Wq  = d_in[1];
    const void* bq  = d_in[2];
    const void* Wk  = d_in[3];
    const void* bk  = d_in[4];
    const void* Wv  = d_in[5];
    const void* bv  = d_in[6];
    const void* Wfc = d_in[7];
    const void* bfc = d_in[8];

    char* ws = (char*)d_ws;
    const size_t SZ_F  = (size_t)M_TOT * DM * sizeof(float);  // 6,291,456
    const size_t SZ_XB = (size_t)M_TOT * DM * 2;              // 3,145,728
    const size_t SZ_WB = (size_t)NQKV * DM * 2;               // 3,538,944
    float* Qf  = (float*)(ws);
    float* Kf  = (float*)(ws + SZ_F);
    float* Vf  = (float*)(ws + 2 * SZ_F);
    u16* Xhi   = (u16*)(ws + 3 * SZ_F);
    u16* Xlo   = (u16*)(ws + 3 * SZ_F + SZ_XB);
    u16* Whi   = (u16*)(ws + 3 * SZ_F + 2 * SZ_XB);
    u16* Wlo   = (u16*)(ws + 3 * SZ_F + 2 * SZ_XB + SZ_WB);
    float* pooled = (float*)(ws + 3 * SZ_F + 2 * SZ_XB + 2 * SZ_WB);
    int* flag  = (int*)(pooled + BATCH * DM);

    hipMemsetAsync(pooled, 0, (size_t)BATCH * DM * sizeof(float), stream);

    detect_dtype<<<1, 256, 0, stream>>>((const u16*)X, flag);

    convert_x<<<768, 256, 0, stream>>>(X, flag, Xhi, Xlo);

    transpose_w<<<dim3(36, 12), 256, 0, stream>>>(Wq, Wk, Wv, flag, Whi, Wlo);

    qkv_gemm_mfma<<<dim3(18, 16), 256, 0, stream>>>(
        Xhi, Xlo, Whi, Wlo, bq, bk, bv, flag, Qf, Kf, Vf);

    attn_pool_f<<<dim3(16, NH, BATCH), 256, 0, stream>>>(Qf, Kf, Vf, pooled);

    fc_relu_f<<<12, 256, 0, stream>>>(pooled, Wfc, bfc, flag, d_out);
}

// Round 5
// 165.501 us; speedup vs baseline: 2.2505x; 1.2300x over previous
//
#include <hip/hip_runtime.h>
#include <hip/hip_bf16.h>
#include <stdint.h>

#define S_LEN 1024
#define BATCH 2
#define DM    768
#define NH    12
#define HD    64
#define W1    32
#define WIN   65
#define NQKV  2304
#define M_TOT 2048

typedef unsigned short u16;
typedef __attribute__((ext_vector_type(4))) float f4;
typedef __attribute__((ext_vector_type(4))) unsigned short us4;
typedef __attribute__((ext_vector_type(8))) unsigned short ushort8;
typedef __attribute__((ext_vector_type(8))) __bf16 bf16x8;
typedef __attribute__((ext_vector_type(4))) float f32x4;

__device__ inline float bf2f(u16 x) {
    union { unsigned u; float f; } z;
    z.u = ((unsigned)x) << 16;
    return z.f;
}
__device__ inline u16 f2bf(float x) {
    union { float f; unsigned u; } z;
    z.f = x;
    unsigned r = z.u + 0x7FFF + ((z.u >> 16) & 1);   // RNE
    return (u16)(r >> 16);
}
// flag==1: buffer holds float32; flag==0: buffer holds bf16
__device__ inline float loadF(const void* p, long i, int f) {
    return f ? ((const float*)p)[i] : bf2f(((const u16*)p)[i]);
}

// ---------------------------------------------------------------------------
// Kernel 0: dtype detector (kept for safety; confirmed f32 in R2).
// ---------------------------------------------------------------------------
__global__ void detect_dtype(const u16* __restrict__ x, int* __restrict__ flag) {
    __shared__ int cnt;
    if (threadIdx.x == 0) cnt = 0;
    __syncthreads();
    int w = 0;
    for (int i = threadIdx.x; i < 512; i += 256) {
        int e = (x[i] >> 7) & 0xFF;
        if (e >= 134) w++;
    }
    atomicAdd(&cnt, w);
    __syncthreads();
    if (threadIdx.x == 0) *flag = (cnt >= 32) ? 1 : 0;
}

// ---------------------------------------------------------------------------
// Kernel 1: X (f32 or bf16) -> Xhi, Xlo (bf16 split). 8 elems/thread.
// ---------------------------------------------------------------------------
__global__ __launch_bounds__(256) void convert_x(
    const void* __restrict__ X, const int* __restrict__ flag,
    u16* __restrict__ hi, u16* __restrict__ lo) {
    const int f = *flag;
    const long base = (long)(blockIdx.x * 256 + threadIdx.x) * 8;
    float v[8];
    if (f) {
        f4 a = *(const f4*)&((const float*)X)[base];
        f4 b = *(const f4*)&((const float*)X)[base + 4];
        v[0]=a.x; v[1]=a.y; v[2]=a.z; v[3]=a.w;
        v[4]=b.x; v[5]=b.y; v[6]=b.z; v[7]=b.w;
    } else {
        ushort8 a = *(const ushort8*)&((const u16*)X)[base];
        #pragma unroll
        for (int j = 0; j < 8; ++j) v[j] = bf2f(a[j]);
    }
    ushort8 h, l;
    #pragma unroll
    for (int j = 0; j < 8; ++j) {
        u16 hb = f2bf(v[j]);
        h[j] = hb;
        l[j] = f2bf(v[j] - bf2f(hb));
    }
    *(ushort8*)&hi[base] = h;
    *(ushort8*)&lo[base] = l;
}

// ---------------------------------------------------------------------------
// Kernel 2: transpose+concat+split weights -> Wt_hi/Wt_lo [n][k], n in [0,2304)
// ---------------------------------------------------------------------------
__global__ __launch_bounds__(256) void transpose_w(
    const void* __restrict__ Wq, const void* __restrict__ Wk,
    const void* __restrict__ Wv, const int* __restrict__ flag,
    u16* __restrict__ Whi, u16* __restrict__ Wlo) {
    __shared__ float tile[64][68];
    const int f = *flag;
    const int n0 = blockIdx.x * 64;     // 0..2240
    const int k0 = blockIdx.y * 64;     // 0..704
    const int sel = n0 / DM;
    const int nl0 = n0 % DM;
    const void* W = (sel == 0) ? Wq : ((sel == 1) ? Wk : Wv);
    const int t = threadIdx.x;
    const int r = t >> 3;               // 0..31
    const int cg = t & 7;               // 0..7

    #pragma unroll
    for (int p = 0; p < 2; ++p) {
        int rr = r + p * 32;            // source row (k)
        long gb = (long)(k0 + rr) * DM + nl0 + cg * 8;
        if (f) {
            f4 a = *(const f4*)&((const float*)W)[gb];
            f4 b = *(const f4*)&((const float*)W)[gb + 4];
            *(f4*)&tile[rr][cg * 8] = a;
            *(f4*)&tile[rr][cg * 8 + 4] = b;
        } else {
            ushort8 a = *(const ushort8*)&((const u16*)W)[gb];
            #pragma unroll
            for (int j = 0; j < 8; ++j) tile[rr][cg * 8 + j] = bf2f(a[j]);
        }
    }
    __syncthreads();
    #pragma unroll
    for (int p = 0; p < 2; ++p) {
        int rn = r + p * 32;            // output row (n)
        ushort8 h, l;
        #pragma unroll
        for (int jj = 0; jj < 8; ++jj) {
            float v = tile[cg * 8 + jj][rn];
            u16 hb = f2bf(v);
            h[jj] = hb;
            l[jj] = f2bf(v - bf2f(hb));
        }
        long ob = (long)(n0 + rn) * DM + k0 + cg * 8;
        *(ushort8*)&Whi[ob] = h;
        *(ushort8*)&Wlo[ob] = l;
    }
}

// ---------------------------------------------------------------------------
// Kernel 3: fused QKV GEMM via split-bf16 MFMA (hh + hl + lh).
// Outputs: Qhi/Qlo/Khi/Klo bf16 [2048][768] (d-contig), Vt bf16 [b][h][d][s].
// ---------------------------------------------------------------------------
__global__ __launch_bounds__(256) void qkv_gemm_mfma(
    const u16* __restrict__ Xhi, const u16* __restrict__ Xlo,
    const u16* __restrict__ Whi, const u16* __restrict__ Wlo,
    const void* __restrict__ bq, const void* __restrict__ bk,
    const void* __restrict__ bv, const int* __restrict__ flag,
    u16* __restrict__ Qhi, u16* __restrict__ Qlo,
    u16* __restrict__ Khi, u16* __restrict__ Klo,
    u16* __restrict__ Vt) {
    __shared__ u16 As[2][128 * 64];   // [hi/lo][row*8+swizzled chunk][8]
    __shared__ u16 Bs[2][128 * 64];

    const int nt = blockIdx.x;      // 0..17
    const int mt = blockIdx.y;      // 0..15
    const int m0 = mt * 128;
    const int n0 = nt * 128;
    const int t = threadIdx.x;
    const int lane = t & 63;
    const int w = t >> 6;
    const int wm = (w >> 1) * 64;
    const int wn = (w & 1) * 64;
    const int lrow = lane & 15;
    const int lq = lane >> 4;
    const int smrow = t >> 3;       // 0..31
    const int skc = t & 7;          // 0..7

    const f32x4 fzero = {0.f, 0.f, 0.f, 0.f};
    f32x4 acc[4][4];
    #pragma unroll
    for (int i = 0; i < 4; ++i)
        #pragma unroll
        for (int j = 0; j < 4; ++j) acc[i][j] = fzero;

    for (int kk = 0; kk < DM; kk += 64) {
        __syncthreads();
        #pragma unroll
        for (int p = 0; p < 4; ++p) {
            int mrow = smrow + p * 32;
            int sw = skc ^ (mrow & 7);
            long ga = (long)(m0 + mrow) * DM + kk + skc * 8;
            long gb = (long)(n0 + mrow) * DM + kk + skc * 8;
            *(ushort8*)&As[0][(mrow * 8 + sw) * 8] = *(const ushort8*)&Xhi[ga];
            *(ushort8*)&As[1][(mrow * 8 + sw) * 8] = *(const ushort8*)&Xlo[ga];
            *(ushort8*)&Bs[0][(mrow * 8 + sw) * 8] = *(const ushort8*)&Whi[gb];
            *(ushort8*)&Bs[1][(mrow * 8 + sw) * 8] = *(const ushort8*)&Wlo[gb];
        }
        __syncthreads();
        #pragma unroll
        for (int kh = 0; kh < 2; ++kh) {
            const int c = kh * 4 + lq;
            bf16x8 ah[4], al[4], bh[4], bl[4];
            #pragma unroll
            for (int i = 0; i < 4; ++i) {
                int ar = wm + i * 16 + lrow;
                int off = (ar * 8 + (c ^ (ar & 7))) * 8;
                ah[i] = *(const bf16x8*)&As[0][off];
                al[i] = *(const bf16x8*)&As[1][off];
            }
            #pragma unroll
            for (int i = 0; i < 4; ++i) {
                int br = wn + i * 16 + lrow;
                int off = (br * 8 + (c ^ (br & 7))) * 8;
                bh[i] = *(const bf16x8*)&Bs[0][off];
                bl[i] = *(const bf16x8*)&Bs[1][off];
            }
            #pragma unroll
            for (int i = 0; i < 4; ++i)
                #pragma unroll
                for (int j = 0; j < 4; ++j) {
                    acc[i][j] = __builtin_amdgcn_mfma_f32_16x16x32_bf16(
                        al[i], bh[j], acc[i][j], 0, 0, 0);
                    acc[i][j] = __builtin_amdgcn_mfma_f32_16x16x32_bf16(
                        ah[i], bl[j], acc[i][j], 0, 0, 0);
                    acc[i][j] = __builtin_amdgcn_mfma_f32_16x16x32_bf16(
                        ah[i], bh[j], acc[i][j], 0, 0, 0);
                }
        }
    }

    const int f = *flag;
    const int region = n0 / DM;     // 0=Q, 1=K, 2=V
    const int nc0 = (n0 % DM) + wn;
    const void* bias = (region == 0) ? bq : ((region == 1) ? bk : bv);

    if (region < 2) {
        u16* Hi = (region == 0) ? Qhi : Khi;
        u16* Lo = (region == 0) ? Qlo : Klo;
        #pragma unroll
        for (int j = 0; j < 4; ++j) {
            int col = nc0 + j * 16 + lrow;
            float bval = loadF(bias, col, f);
            #pragma unroll
            for (int i = 0; i < 4; ++i) {
                int row = m0 + wm + i * 16 + lq * 4;
                #pragma unroll
                for (int r = 0; r < 4; ++r) {
                    float v = acc[i][j][r] + bval;
                    u16 hb = f2bf(v);
                    long oi = (long)(row + r) * DM + col;
                    Hi[oi] = hb;
                    Lo[oi] = f2bf(v - bf2f(hb));
                }
            }
        }
    } else {
        // V: write transposed bf16 Vt[b][h][dloc][s]
        #pragma unroll
        for (int j = 0; j < 4; ++j) {
            int col = nc0 + j * 16 + lrow;       // v-dim 0..767
            int h = col >> 6, dloc = col & 63;
            float bval = loadF(bias, col, f);
            #pragma unroll
            for (int i = 0; i < 4; ++i) {
                int row = m0 + wm + i * 16 + lq * 4;   // global s (incl batch)
                int b = row >> 10, sl = row & 1023;
                us4 pk;
                #pragma unroll
                for (int r = 0; r < 4; ++r) pk[r] = f2bf(acc[i][j][r] + bval);
                *(us4*)&Vt[(((long)(b * NH + h) * 64 + dloc) << 10) + sl] = pk;
            }
        }
    }
}

// ---------------------------------------------------------------------------
// Kernel 4: MFMA flash attention + pooled sum.
// Block (b, h, 64 queries); wave w = 16-query tile. Scores: split-bf16 MFMA
// with Q/K fragments gathered directly from global (row-contiguous 64B).
// Softmax f32 in C-layout; P->LDS (A-layout); PV via MFMA with Vt staged LDS.
// ---------------------------------------------------------------------------
__global__ __launch_bounds__(256) void attn_pool_mfma(
    const u16* __restrict__ Qhi, const u16* __restrict__ Qlo,
    const u16* __restrict__ Khi, const u16* __restrict__ Klo,
    const u16* __restrict__ Vt, float* __restrict__ pooled) {
    __shared__ u16 vt[64][136];        // V^T window: [d][key 128 + pad]
    __shared__ u16 pl[4][16][136];     // per-wave P: [wave][query row][key]
    const int b = blockIdx.z, h = blockIdx.y;
    const int s0 = blockIdx.x * 64;
    const int t = threadIdx.x;
    const int k0 = s0 - 32;

    // stage V^T window (coalesced; clamp at sequence edges - masked later)
    const u16* vtg = Vt + ((size_t)(b * NH + h) * 64) * 1024;
    #pragma unroll
    for (int it = 0; it < 4; ++it) {
        int item = it * 256 + t;
        int d = item >> 4, kc = item & 15;
        int kbase = k0 + kc * 8;
        if (kbase >= 0 && kbase + 7 < S_LEN) {
            *(ushort8*)&vt[d][kc * 8] = *(const ushort8*)&vtg[d * 1024 + kbase];
        } else {
            #pragma unroll
            for (int j = 0; j < 8; ++j) {
                int kk = kbase + j;
                int kcl = kk < 0 ? 0 : (kk > S_LEN - 1 ? S_LEN - 1 : kk);
                vt[d][kc * 8 + j] = vtg[d * 1024 + kcl];
            }
        }
    }
    __syncthreads();

    const int w = t >> 6, lane = t & 63;
    const int cl = lane & 15, q = lane >> 4;

    // ---- scores: S = Q . K^T (split-bf16, 3 mfma per tile) ----
    const f32x4 fzero = {0.f, 0.f, 0.f, 0.f};
    f32x4 accS[8];
    #pragma unroll
    for (int n = 0; n < 8; ++n) accS[n] = fzero;

    const long qrow = (long)(b * S_LEN + s0 + w * 16 + cl);
    bf16x8 aqh[2], aql[2];
    #pragma unroll
    for (int ks = 0; ks < 2; ++ks) {
        long qa = qrow * DM + h * HD + ks * 32 + q * 8;
        aqh[ks] = *(const bf16x8*)&Qhi[qa];
        aql[ks] = *(const bf16x8*)&Qlo[qa];
    }
    #pragma unroll
    for (int n = 0; n < 8; ++n) {
        int key = k0 + n * 16 + cl;
        int kcl = key < 0 ? 0 : (key > S_LEN - 1 ? S_LEN - 1 : key);
        long ka = (long)(b * S_LEN + kcl) * DM + h * HD;
        #pragma unroll
        for (int ks = 0; ks < 2; ++ks) {
            bf16x8 bkh = *(const bf16x8*)&Khi[ka + ks * 32 + q * 8];
            bf16x8 bkl = *(const bf16x8*)&Klo[ka + ks * 32 + q * 8];
            accS[n] = __builtin_amdgcn_mfma_f32_16x16x32_bf16(aql[ks], bkh, accS[n], 0, 0, 0);
            accS[n] = __builtin_amdgcn_mfma_f32_16x16x32_bf16(aqh[ks], bkl, accS[n], 0, 0, 0);
            accS[n] = __builtin_amdgcn_mfma_f32_16x16x32_bf16(aqh[ks], bkh, accS[n], 0, 0, 0);
        }
    }

    // ---- softmax (unnormalized) in C-layout: col=cl(key), row=q*4+r ----
    float l4[4] = {0.f, 0.f, 0.f, 0.f};
    #pragma unroll
    for (int n = 0; n < 8; ++n) {
        int key = k0 + n * 16 + cl;
        #pragma unroll
        for (int r = 0; r < 4; ++r) {
            int s = s0 + w * 16 + q * 4 + r;
            bool valid = (key >= s - W1) && (key <= s + W1) && (key >= 0) && (key < S_LEN);
            float p = valid ? __expf(accS[n][r] * 0.125f) : 0.f;
            accS[n][r] = p;
            l4[r] += p;
        }
    }
    #pragma unroll
    for (int m = 1; m <= 8; m <<= 1)
        #pragma unroll
        for (int r = 0; r < 4; ++r) l4[r] += __shfl_xor(l4[r], m, 64);

    // ---- P -> LDS in A-layout ----
    #pragma unroll
    for (int n = 0; n < 8; ++n)
        #pragma unroll
        for (int r = 0; r < 4; ++r)
            pl[w][q * 4 + r][n * 16 + cl] = f2bf(accS[n][r]);

    // ---- O = P . V (MFMA over 4 key-chunks of 32) ----
    f32x4 accO[4];
    #pragma unroll
    for (int n = 0; n < 4; ++n) accO[n] = fzero;
    bf16x8 ap[4];
    #pragma unroll
    for (int ks = 0; ks < 4; ++ks)
        ap[ks] = *(const bf16x8*)&pl[w][cl][ks * 32 + q * 8];
    #pragma unroll
    for (int n = 0; n < 4; ++n)
        #pragma unroll
        for (int ks = 0; ks < 4; ++ks) {
            bf16x8 bv = *(const bf16x8*)&vt[n * 16 + cl][ks * 32 + q * 8];
            accO[n] = __builtin_amdgcn_mfma_f32_16x16x32_bf16(ap[ks], bv, accO[n], 0, 0, 0);
        }

    // ---- normalize rows, pool over queries, atomic into pooled ----
    float rcp4[4];
    #pragma unroll
    for (int r = 0; r < 4; ++r) rcp4[r] = 1.0f / l4[r];
    #pragma unroll
    for (int n = 0; n < 4; ++n) {
        float pp = 0.f;
        #pragma unroll
        for (int r = 0; r < 4; ++r) pp += accO[n][r] * rcp4[r];
        pp += __shfl_xor(pp, 16, 64);
        pp += __shfl_xor(pp, 32, 64);
        if (q == 0)
            atomicAdd(&pooled[b * DM + h * HD + n * 16 + cl], pp);
    }
}

// ---------------------------------------------------------------------------
// Kernel 5: out = relu(pooled/S @ Wfc + bfc); flag-based load/store.
// ---------------------------------------------------------------------------
__global__ __launch_bounds__(256) void fc_relu_f(
    const float* __restrict__ pooled, const void* __restrict__ Wfc,
    const void* __restrict__ bfc, const int* __restrict__ flag,
    void* __restrict__ out) {
    __shared__ float red[2][4][64];
    const int f = *flag;
    const int t = threadIdx.x;
    const int nb = blockIdx.x;          // 0..11
    const int nn = t & 63;
    const int dg = t >> 6;              // 0..3
    const int n = nb * 64 + nn;
    float s0 = 0.f, s1 = 0.f;
    for (int d = dg * 192; d < dg * 192 + 192; ++d) {
        float wv = loadF(Wfc, (long)d * DM + n, f);
        s0 += pooled[d] * wv;
        s1 += pooled[DM + d] * wv;
    }
    red[0][dg][nn] = s0;
    red[1][dg][nn] = s1;
    __syncthreads();
    if (t < 128) {
        int bb = t >> 6;
        int n2 = t & 63;
        float sum = red[bb][0][n2] + red[bb][1][n2] + red[bb][2][n2] + red[bb][3][n2];
        sum = sum * (1.0f / (float)S_LEN) + loadF(bfc, nb * 64 + n2, f);
        sum = sum > 0.f ? sum : 0.f;
        int oi = bb * DM + nb * 64 + n2;
        if (f) ((float*)out)[oi] = sum;
        else   ((u16*)out)[oi]  = f2bf(sum);
    }
}

// ---------------------------------------------------------------------------
extern "C" void kernel_launch(void* const* d_in, const int* in_sizes, int n_in,
                              void* d_out, int out_size, void* d_ws, size_t ws_size,
                              hipStream_t stream) {
    const void* X   = d_in[0];
    const void* Wq  = d_in[1];
    const void* bq  = d_in[2];
    const void* Wk  = d_in[3];
    const void* bk  = d_in[4];
    const void* Wv  = d_in[5];
    const void* bv  = d_in[6];
    const void* Wfc = d_in[7];
    const void* bfc = d_in[8];

    char* ws = (char*)d_ws;
    const size_t SZ_XB = (size_t)M_TOT * DM * 2;              // 3,145,728
    const size_t SZ_WB = (size_t)NQKV * DM * 2;               // 3,538,944
    u16* Xhi = (u16*)(ws);
    u16* Xlo = (u16*)(ws + SZ_XB);
    u16* Whi = (u16*)(ws + 2 * SZ_XB);
    u16* Wlo = (u16*)(ws + 2 * SZ_XB + SZ_WB);
    u16* Qhi = (u16*)(ws + 2 * SZ_XB + 2 * SZ_WB);
    u16* Qlo = (u16*)(ws + 3 * SZ_XB + 2 * SZ_WB);
    u16* Khi = (u16*)(ws + 4 * SZ_XB + 2 * SZ_WB);
    u16* Klo = (u16*)(ws + 5 * SZ_XB + 2 * SZ_WB);
    u16* Vt  = (u16*)(ws + 6 * SZ_XB + 2 * SZ_WB);
    float* pooled = (float*)(ws + 7 * SZ_XB + 2 * SZ_WB);
    int* flag = (int*)(pooled + BATCH * DM);

    (void)hipMemsetAsync(pooled, 0, (size_t)BATCH * DM * sizeof(float), stream);

    detect_dtype<<<1, 256, 0, stream>>>((const u16*)X, flag);

    convert_x<<<768, 256, 0, stream>>>(X, flag, Xhi, Xlo);

    transpose_w<<<dim3(36, 12), 256, 0, stream>>>(Wq, Wk, Wv, flag, Whi, Wlo);

    qkv_gemm_mfma<<<dim3(18, 16), 256, 0, stream>>>(
        Xhi, Xlo, Whi, Wlo, bq, bk, bv, flag,
        Qhi, Qlo, Khi, Klo, Vt);

    attn_pool_mfma<<<dim3(16, NH, BATCH), 256, 0, stream>>>(
        Qhi, Qlo, Khi, Klo, Vt, pooled);

    fc_relu_f<<<12, 256, 0, stream>>>(pooled, Wfc, bfc, flag, d_out);
}